// Round 7
// baseline (732.552 us; speedup 1.0000x reference)
//
#include <hip/hip_runtime.h>

#define N_NODES 100000
#define N_NODES_PAD 100032   // 1563 * 64
#define N_EDGES 200000
#define N_GRAPHS 4096
#define D 256
#define D2 512
#define OUTD 768
#define LAYERS 4
#define NODE_FEATS 9
#define EDGE_FEATS 3
#define NODE_VOCAB 119
#define EDGE_VOCAB 22
#define BM 64            // rows per MLP block
#define GB 8             // graphs per final block

typedef __attribute__((ext_vector_type(8))) short bf16x8;
typedef __attribute__((ext_vector_type(4))) float f32x4;
typedef unsigned short ushort_t;
typedef unsigned int uint_t;

__device__ __forceinline__ ushort_t f2b(float f) {   // f32 -> bf16 bits, RNE
    union { float f; uint_t u; } x; x.f = f;
    uint_t r = (x.u + 0x7FFFu + ((x.u >> 16) & 1u)) >> 16;
    return (ushort_t)r;
}
__device__ __forceinline__ float b2f(ushort_t u) {
    union { uint_t u; float f; } x; x.u = ((uint_t)u) << 16;
    return x.f;
}

__device__ __forceinline__ int lower_bound_i(const int* a, int n, int v) {
    int lo = 0, hi = n;
    while (lo < hi) { int mid = (lo + hi) >> 1; if (a[mid] < v) lo = mid + 1; else hi = mid; }
    return lo;
}

// ---------------- embedding encode (nodes), bf16 out ----------------
__global__ __launch_bounds__(256) void encode_nodes_k(const int* __restrict__ xcat,
                                                      const float* __restrict__ tab,
                                                      ushort_t* __restrict__ X) {
    int n = blockIdx.x, d = threadIdx.x;
    float acc = 0.f;
#pragma unroll
    for (int f = 0; f < NODE_FEATS; ++f) {
        int idx = xcat[n * NODE_FEATS + f];
        acc += tab[((size_t)f * NODE_VOCAB + idx) * D + d];
    }
    X[(size_t)n * D + d] = f2b(acc);
}

// ---------------- CSR build ----------------
__global__ __launch_bounds__(256) void count_k(const int* __restrict__ eidx, int* deg) {
    int e = blockIdx.x * 256 + threadIdx.x;
    if (e < N_EDGES) atomicAdd(&deg[eidx[N_EDGES + e]], 1);
}

#define SCAN_B 1024
__global__ __launch_bounds__(256) void scan1_k(const int* __restrict__ deg,
                                               int* __restrict__ excl, int* __restrict__ bsum) {
    __shared__ int sh[256];
    int b = blockIdx.x, t = threadIdx.x;
    int base = b * SCAN_B + t * 4;
    int d0 = (base + 0) < N_NODES ? deg[base + 0] : 0;
    int d1 = (base + 1) < N_NODES ? deg[base + 1] : 0;
    int d2 = (base + 2) < N_NODES ? deg[base + 2] : 0;
    int d3 = (base + 3) < N_NODES ? deg[base + 3] : 0;
    int s = d0 + d1 + d2 + d3;
    sh[t] = s; __syncthreads();
    for (int off = 1; off < 256; off <<= 1) {
        int x = (t >= off) ? sh[t - off] : 0;
        __syncthreads();
        sh[t] += x;
        __syncthreads();
    }
    int incl = sh[t];
    int ex = incl - s;
    if (base + 0 < N_NODES) excl[base + 0] = ex;
    if (base + 1 < N_NODES) excl[base + 1] = ex + d0;
    if (base + 2 < N_NODES) excl[base + 2] = ex + d0 + d1;
    if (base + 3 < N_NODES) excl[base + 3] = ex + d0 + d1 + d2;
    if (t == 255) bsum[b] = incl;
}

__global__ void scan2_k(int* bsum, int nb) {   // 1 block of 128 threads
    __shared__ int sh[128];
    int t = threadIdx.x;
    int v = (t < nb) ? bsum[t] : 0;
    sh[t] = v; __syncthreads();
    for (int off = 1; off < 128; off <<= 1) {
        int x = (t >= off) ? sh[t - off] : 0;
        __syncthreads();
        sh[t] += x;
        __syncthreads();
    }
    if (t < nb) bsum[t] = sh[t] - v;   // exclusive over blocks
}

__global__ __launch_bounds__(256) void scan3_k(int* __restrict__ offs, int* __restrict__ cursor,
                                               const int* __restrict__ bsum) {
    int i = blockIdx.x * 256 + threadIdx.x;
    if (i < N_NODES) {
        int v = offs[i] + bsum[i >> 10];
        offs[i] = v;
        cursor[i] = v;
    }
}

// elist entry: {src node, packed edge attrs}
__global__ __launch_bounds__(256) void fill_k(const int* __restrict__ eidx,
                                              const int* __restrict__ eattr,
                                              int* cursor, int2* __restrict__ elist) {
    int e = blockIdx.x * 256 + threadIdx.x;
    if (e < N_EDGES) {
        int src = eidx[e];
        int dst = eidx[N_EDGES + e];
        int pa = eattr[e * EDGE_FEATS + 0] | (eattr[e * EDGE_FEATS + 1] << 8)
               | (eattr[e * EDGE_FEATS + 2] << 16);
        int pos = atomicAdd(&cursor[dst], 1);
        elist[pos] = make_int2(src, pa);
    }
}

// ---------------- weight pre-pack into MFMA fragment layout (bf16) ----------------
__global__ __launch_bounds__(256) void pack1_k(const float* __restrict__ W1, ushort_t* __restrict__ apack) {
    size_t i = (size_t)blockIdx.x * 256 + threadIdx.x;   // 65536 groups
    int l = (int)(i >> 14);
    int rem = (int)(i & 16383);
    int ntg = rem >> 9;
    int rem2 = rem & 511;
    int kk = rem2 >> 6;
    int lane = rem2 & 63;
    int n = ntg * 16 + (lane & 15);
    int k0 = kk * 32 + (lane >> 4) * 8;
    const float* w = W1 + ((size_t)l * D + k0) * D2 + n;
    ushort_t* o = apack + i * 8;
#pragma unroll
    for (int j = 0; j < 8; ++j) o[j] = f2b(w[(size_t)j * D2]);
}

__global__ __launch_bounds__(256) void pack2_k(const float* __restrict__ W2, ushort_t* __restrict__ bpack) {
    size_t i = (size_t)blockIdx.x * 256 + threadIdx.x;   // 65536 groups
    int l = (int)(i >> 14);
    int rem = (int)(i & 16383);
    int ntg = rem >> 10;
    int rem2 = rem & 1023;
    int kk = rem2 >> 6;
    int lane = rem2 & 63;
    int n = ntg * 16 + (lane & 15);
    int k0 = kk * 32 + (lane >> 4) * 8;
    const float* w = W2 + ((size_t)l * D2 + k0) * D + n;
    ushort_t* o = bpack + i * 8;
#pragma unroll
    for (int j = 0; j < 8; ++j) o[j] = f2b(w[(size_t)j * D]);
}

// ------ fused gather + MFMA MLP: Xout = relu(relu(gather(Xin)@W1+b1)@W2+b2) ------
// 512 threads = 8 waves, BM=64 rows, 64KB LDS -> 2 blocks/CU.
// Wave gathers 8 rows directly into swizzled hA; GEMMs unchanged; coalesced epilogue.
__global__ __launch_bounds__(512, 4) void mlp_k(const ushort4* __restrict__ X4in,
                                                const float4* __restrict__ eemb4,
                                                const int* __restrict__ offs,
                                                const int* __restrict__ deg,
                                                const int2* __restrict__ elist,
                                                const ushort_t* __restrict__ apack,
                                                const float* __restrict__ b1,
                                                const ushort_t* __restrict__ bpack,
                                                const float* __restrict__ b2,
                                                ushort_t* __restrict__ Xout) {
    __shared__ __align__(16) char hA[BM * 512];    // 32KB: 64 rows x 256 bf16, swizzled
    __shared__ __align__(16) char midh[BM * 512];  // 32KB: one n-half of mid / out stage
    const int t = threadIdx.x;
    const int wid = t >> 6, lane = t & 63;
    const int l15 = lane & 15, g = lane >> 4;
    const size_t r0 = (size_t)blockIdx.x * BM;

    bf16x8 AfA[2], AfB[2], WfA[2], WfB[2];
    // prefetch GEMM1 half-0 first fragments (hides under gather)
#pragma unroll
    for (int nt = 0; nt < 2; ++nt)
        AfA[nt] = *(const bf16x8*)(apack + ((size_t)((0 * 16 + wid * 2 + nt) * 8 + 0) * 64 + lane) * 8);

    // ---- gather phase: wave wid produces rows wid*8 .. wid*8+7 into hA ----
#pragma unroll
    for (int i = 0; i < 8; ++i) {
        int row = wid * 8 + i;
        int n = (int)r0 + row;
        float acc[4] = {0.f, 0.f, 0.f, 0.f};
        if (n < N_NODES) {
            ushort4 xv = X4in[(size_t)n * 64 + lane];
            acc[0] = b2f(xv.x); acc[1] = b2f(xv.y); acc[2] = b2f(xv.z); acc[3] = b2f(xv.w);
            int start = offs[n], dg = deg[n];
            if (dg > 0) {
                int2 sp = elist[start];
                ushort4 sv = X4in[(size_t)sp.x * 64 + lane];
                for (int e = 0; e < dg; ++e) {
                    int2 spn = sp; ushort4 svn = sv;
                    if (e + 1 < dg) {
                        spn = elist[start + e + 1];
                        svn = X4in[(size_t)spn.x * 64 + lane];
                    }
                    float4 t0 = eemb4[(size_t)((sp.y      ) & 255) * 64 + lane];
                    float4 t1 = eemb4[((size_t)EDGE_VOCAB + ((sp.y >> 8) & 255)) * 64 + lane];
                    float4 t2 = eemb4[((size_t)2 * EDGE_VOCAB + ((sp.y >> 16) & 255)) * 64 + lane];
                    acc[0] += fmaxf(b2f(sv.x) + t0.x + t1.x + t2.x, 0.f);
                    acc[1] += fmaxf(b2f(sv.y) + t0.y + t1.y + t2.y, 0.f);
                    acc[2] += fmaxf(b2f(sv.z) + t0.z + t1.z + t2.z, 0.f);
                    acc[3] += fmaxf(b2f(sv.w) + t0.w + t1.w + t2.w, 0.f);
                    sp = spn; sv = svn;
                }
            }
        }
        uint2 pk;
        pk.x = (uint_t)f2b(acc[0]) | ((uint_t)f2b(acc[1]) << 16);
        pk.y = (uint_t)f2b(acc[2]) | ((uint_t)f2b(acc[3]) << 16);
        *(uint2*)(hA + ((row * 512 + lane * 8) ^ ((row & 7) << 4))) = pk;
    }
    __syncthreads();

    f32x4 acc2[2][4];
#pragma unroll
    for (int a = 0; a < 2; ++a)
#pragma unroll
        for (int b = 0; b < 4; ++b) { f32x4 z = {0.f,0.f,0.f,0.f}; acc2[a][b] = z; }

#pragma unroll
    for (int half = 0; half < 2; ++half) {
        // ---- GEMM1 (transposed): mid[:, half*256 + wid*32 ...] ----
        f32x4 acc1[2][4];
#pragma unroll
        for (int a = 0; a < 2; ++a)
#pragma unroll
            for (int b = 0; b < 4; ++b) { f32x4 z = {0.f,0.f,0.f,0.f}; acc1[a][b] = z; }

#pragma unroll
        for (int kk = 0; kk < 8; ++kk) {
            bf16x8 Bf[4];
#pragma unroll
            for (int mt = 0; mt < 4; ++mt) {
                int m = mt * 16 + l15;
                Bf[mt] = *(const bf16x8*)(hA + ((m * 512 + (kk * 32 + g * 8) * 2) ^ ((m & 7) << 4)));
            }
            bf16x8* cur = (kk & 1) ? AfB : AfA;   // kk is compile-time under unroll
            bf16x8* nxt = (kk & 1) ? AfA : AfB;
            if (kk < 7) {
#pragma unroll
                for (int nt = 0; nt < 2; ++nt)
                    nxt[nt] = *(const bf16x8*)(apack +
                        ((size_t)((half * 16 + wid * 2 + nt) * 8 + kk + 1) * 64 + lane) * 8);
            }
            __builtin_amdgcn_s_setprio(1);
#pragma unroll
            for (int nt = 0; nt < 2; ++nt)
#pragma unroll
                for (int mt = 0; mt < 4; ++mt)
                    acc1[nt][mt] = __builtin_amdgcn_mfma_f32_16x16x32_bf16(cur[nt], Bf[mt], acc1[nt][mt], 0, 0, 0);
            __builtin_amdgcn_s_setprio(0);
        }

        // prefetch GEMM2 first W2 fragments for this half (hides under pack + barrier)
#pragma unroll
        for (int nt = 0; nt < 2; ++nt)
            WfA[nt] = *(const bf16x8*)(bpack +
                ((size_t)((wid * 2 + nt) * 16 + half * 8 + 0) * 64 + lane) * 8);

        // bias + relu + pack to midh (lane holds 4 consecutive n at fixed m)
#pragma unroll
        for (int nt = 0; nt < 2; ++nt) {
            int n0l = (wid * 2 + nt) * 16 + g * 4;             // local col in half
            f32x4 bv = *(const f32x4*)(b1 + half * 256 + n0l);
#pragma unroll
            for (int mt = 0; mt < 4; ++mt) {
                int m = mt * 16 + l15;
                ushort_t us[4];
#pragma unroll
                for (int r = 0; r < 4; ++r)
                    us[r] = f2b(fmaxf(acc1[nt][mt][r] + bv[r], 0.f));
                uint2 pk;
                pk.x = (uint_t)us[0] | ((uint_t)us[1] << 16);
                pk.y = (uint_t)us[2] | ((uint_t)us[3] << 16);
                *(uint2*)(midh + ((m * 512 + n0l * 2) ^ ((m & 7) << 4))) = pk;
            }
        }
        __syncthreads();   // midh fully written

        // ---- GEMM2 partial (transposed): acc2 += mid_half @ W2[k-half] ----
#pragma unroll
        for (int kk = 0; kk < 8; ++kk) {
            bf16x8 Mf[4];
#pragma unroll
            for (int mt = 0; mt < 4; ++mt) {
                int m = mt * 16 + l15;
                Mf[mt] = *(const bf16x8*)(midh + ((m * 512 + (kk * 32 + g * 8) * 2) ^ ((m & 7) << 4)));
            }
            bf16x8* cur = (kk & 1) ? WfB : WfA;
            bf16x8* nxt = (kk & 1) ? WfA : WfB;
            if (kk < 7) {
#pragma unroll
                for (int nt = 0; nt < 2; ++nt)
                    nxt[nt] = *(const bf16x8*)(bpack +
                        ((size_t)((wid * 2 + nt) * 16 + half * 8 + kk + 1) * 64 + lane) * 8);
            }
            __builtin_amdgcn_s_setprio(1);
#pragma unroll
            for (int nt = 0; nt < 2; ++nt)
#pragma unroll
                for (int mt = 0; mt < 4; ++mt)
                    acc2[nt][mt] = __builtin_amdgcn_mfma_f32_16x16x32_bf16(cur[nt], Mf[mt], acc2[nt][mt], 0, 0, 0);
            __builtin_amdgcn_s_setprio(0);
        }

        // prefetch next half's GEMM1 first fragments (hides under tail barrier)
        if (half == 0) {
#pragma unroll
            for (int nt = 0; nt < 2; ++nt)
                AfA[nt] = *(const bf16x8*)(apack +
                    ((size_t)((1 * 16 + wid * 2 + nt) * 8 + 0) * 64 + lane) * 8);
        }
        __syncthreads();   // all reads of midh done before next half overwrites
    }

    // ---- epilogue: stage into midh (swizzled), then coalesced 64B/thread store ----
#pragma unroll
    for (int nt = 0; nt < 2; ++nt) {
        int n0 = (wid * 2 + nt) * 16 + g * 4;
        f32x4 bv = *(const f32x4*)(b2 + n0);
#pragma unroll
        for (int mt = 0; mt < 4; ++mt) {
            int m = mt * 16 + l15;
            ushort_t us[4];
#pragma unroll
            for (int r = 0; r < 4; ++r)
                us[r] = f2b(fmaxf(acc2[nt][mt][r] + bv[r], 0.f));
            uint2 pk;
            pk.x = (uint_t)us[0] | ((uint_t)us[1] << 16);
            pk.y = (uint_t)us[2] | ((uint_t)us[3] << 16);
            *(uint2*)(midh + ((m * 512 + n0 * 2) ^ ((m & 7) << 4))) = pk;
        }
    }
    __syncthreads();
    {
        char* dst = (char*)Xout + r0 * 512;
#pragma unroll
        for (int j = 0; j < 4; ++j) {
            int Lb = t * 64 + j * 16;
            int row = Lb >> 9;
            int Sb = Lb ^ ((row & 7) << 4);
            *(uint4*)(dst + Lb) = *(const uint4*)(midh + Sb);
        }
    }
}

// -------- fused pooling + final MLP + L2 normalize, GB=8 graphs per block --------
__global__ __launch_bounds__(256) void final_k(const ushort4* __restrict__ X4,
                                               const int* __restrict__ batch,
                                               const float* __restrict__ pW1,
                                               const float* __restrict__ pb1,
                                               const float* __restrict__ pW2,
                                               const float* __restrict__ pb2,
                                               float* __restrict__ out) {
    __shared__ float gin[GB][D];    // 8KB
    __shared__ float mid[GB][D];    // 8KB
    __shared__ float red[GB][256];  // 8KB
    __shared__ int bnd[GB + 1];
    const int g0 = blockIdx.x * GB, t = threadIdx.x;
    const int wid = t >> 6, lane = t & 63;
    if (t <= GB) bnd[t] = lower_bound_i(batch, N_NODES, g0 + t);
    __syncthreads();

    // pooling: wave wid handles graphs wid and wid+4
#pragma unroll
    for (int qq = 0; qq < 2; ++qq) {
        int q = wid + qq * 4;
        f32x4 a = {0.f, 0.f, 0.f, 0.f};
        for (int n = bnd[q]; n < bnd[q + 1]; ++n) {
            ushort4 v = X4[(size_t)n * 64 + lane];
            a.x += b2f(v.x); a.y += b2f(v.y); a.z += b2f(v.z); a.w += b2f(v.w);
        }
        *(f32x4*)&gin[q][lane * 4] = a;
    }
    __syncthreads();

    // mlp1: mid = relu(gin @ pW1 + pb1)
    {
        float m_[GB];
        float bb = pb1[t];
#pragma unroll
        for (int q = 0; q < GB; ++q) m_[q] = bb;
        for (int k = 0; k < D; ++k) {
            float w = pW1[(size_t)k * D + t];
#pragma unroll
            for (int q = 0; q < GB; ++q) m_[q] += gin[q][k] * w;
        }
#pragma unroll
        for (int q = 0; q < GB; ++q) mid[q][t] = fmaxf(m_[q], 0.f);
    }
    __syncthreads();

    // mlp2 + norm
    float a0[GB], a1[GB], a2[GB];
    {
        float b0 = pb2[t], b1_ = pb2[t + 256], b2_ = pb2[t + 512];
#pragma unroll
        for (int q = 0; q < GB; ++q) { a0[q] = b0; a1[q] = b1_; a2[q] = b2_; }
        for (int k = 0; k < D; ++k) {
            float w0 = pW2[(size_t)k * OUTD + t];
            float w1 = pW2[(size_t)k * OUTD + 256 + t];
            float w2 = pW2[(size_t)k * OUTD + 512 + t];
#pragma unroll
            for (int q = 0; q < GB; ++q) {
                float mv = mid[q][k];
                a0[q] += mv * w0; a1[q] += mv * w1; a2[q] += mv * w2;
            }
        }
    }
#pragma unroll
    for (int q = 0; q < GB; ++q)
        red[q][t] = a0[q] * a0[q] + a1[q] * a1[q] + a2[q] * a2[q];
    __syncthreads();
    for (int s = 128; s > 0; s >>= 1) {
        if (t < s) {
#pragma unroll
            for (int q = 0; q < GB; ++q) red[q][t] += red[q][t + s];
        }
        __syncthreads();
    }
#pragma unroll
    for (int q = 0; q < GB; ++q) {
        float inv = 1.f / fmaxf(sqrtf(red[q][0]), 1e-12f);
        out[(size_t)(g0 + q) * OUTD + t]       = a0[q] * inv;
        out[(size_t)(g0 + q) * OUTD + 256 + t] = a1[q] * inv;
        out[(size_t)(g0 + q) * OUTD + 512 + t] = a2[q] * inv;
    }
}

extern "C" void kernel_launch(void* const* d_in, const int* in_sizes, int n_in,
                              void* d_out, int out_size, void* d_ws, size_t ws_size,
                              hipStream_t stream) {
    const int*   x_cat      = (const int*)d_in[0];
    const int*   edge_attr  = (const int*)d_in[1];
    const int*   edge_index = (const int*)d_in[2];
    const int*   batch      = (const int*)d_in[3];
    const float* node_emb   = (const float*)d_in[4];
    const float* edge_emb   = (const float*)d_in[5];
    const float* W1  = (const float*)d_in[6];
    const float* b1  = (const float*)d_in[7];
    const float* W2  = (const float*)d_in[8];
    const float* b2  = (const float*)d_in[9];
    const float* pW1 = (const float*)d_in[10];
    const float* pb1 = (const float*)d_in[11];
    const float* pW2 = (const float*)d_in[12];
    const float* pb2 = (const float*)d_in[13];
    float* out = (float*)d_out;

    // ---- workspace carve (~112 MB) ----
    char* p = (char*)d_ws;
    auto carve = [&](size_t bytes) { char* q = p; p += (bytes + 255) & ~(size_t)255; return q; };
    ushort_t* Xa     = (ushort_t*)carve((size_t)N_NODES_PAD * D * 2);   // 51.2 MB
    ushort_t* Xb     = (ushort_t*)carve((size_t)N_NODES_PAD * D * 2);   // 51.2 MB
    int*      deg    = (int*)carve((size_t)N_NODES * 4);
    int*      offs   = (int*)carve((size_t)(N_NODES + 8) * 4);
    int*      cursor = (int*)carve((size_t)(N_NODES + 8) * 4);
    int*      bsum   = (int*)carve(1024);
    int2*     elist  = (int2*)carve((size_t)N_EDGES * 8);
    ushort_t* apack1 = (ushort_t*)carve((size_t)LAYERS * 32 * 8 * 64 * 8 * 2);   // 2 MB
    ushort_t* bpack2 = (ushort_t*)carve((size_t)LAYERS * 16 * 16 * 64 * 8 * 2);  // 2 MB

    const int NB = (N_NODES + SCAN_B - 1) / SCAN_B;   // 98

    // ---- one-time per call: weight pre-pack + CSR build ----
    pack1_k<<<256, 256, 0, stream>>>(W1, apack1);
    pack2_k<<<256, 256, 0, stream>>>(W2, bpack2);
    hipMemsetAsync(deg, 0, (size_t)N_NODES * 4, stream);
    count_k<<<(N_EDGES + 255) / 256, 256, 0, stream>>>(edge_index, deg);
    scan1_k<<<NB, 256, 0, stream>>>(deg, offs, bsum);
    scan2_k<<<1, 128, 0, stream>>>(bsum, NB);
    scan3_k<<<(N_NODES + 255) / 256, 256, 0, stream>>>(offs, cursor, bsum);
    fill_k<<<(N_EDGES + 255) / 256, 256, 0, stream>>>(edge_index, edge_attr, cursor, elist);

    encode_nodes_k<<<N_NODES, 256, 0, stream>>>(x_cat, node_emb, Xa);

    ushort_t* xin = Xa;
    ushort_t* xout = Xb;
    for (int l = 0; l < LAYERS; ++l) {
        mlp_k<<<N_NODES_PAD / BM, 512, 0, stream>>>(
            (const ushort4*)xin, (const float4*)edge_emb, offs, deg, elist,
            apack1 + (size_t)l * 32 * 8 * 64 * 8,
            b1 + (size_t)l * D2,
            bpack2 + (size_t)l * 16 * 16 * 64 * 8,
            b2 + (size_t)l * D,
            xout);
        ushort_t* tmp = xin; xin = xout; xout = tmp;
    }

    final_k<<<N_GRAPHS / GB, 256, 0, stream>>>((const ushort4*)xin, batch, pW1, pb1, pW2, pb2, out);
}

// Round 8
// 729.266 us; speedup vs baseline: 1.0045x; 1.0045x over previous
//
#include <hip/hip_runtime.h>

#define N_NODES 100000
#define N_NODES_PAD 100032   // 1563 * 64
#define N_EDGES 200000
#define N_GRAPHS 4096
#define D 256
#define D2 512
#define OUTD 768
#define LAYERS 4
#define NODE_FEATS 9
#define EDGE_FEATS 3
#define NODE_VOCAB 119
#define EDGE_VOCAB 22
#define BM 64            // rows per MLP block
#define GB 8             // graphs per final block

typedef __attribute__((ext_vector_type(8))) short bf16x8;
typedef __attribute__((ext_vector_type(4))) float f32x4;
typedef unsigned short ushort_t;
typedef unsigned int uint_t;

__device__ __forceinline__ ushort_t f2b(float f) {   // f32 -> bf16 bits, RNE
    union { float f; uint_t u; } x; x.f = f;
    uint_t r = (x.u + 0x7FFFu + ((x.u >> 16) & 1u)) >> 16;
    return (ushort_t)r;
}
__device__ __forceinline__ float b2f(ushort_t u) {
    union { uint_t u; float f; } x; x.u = ((uint_t)u) << 16;
    return x.f;
}

__device__ __forceinline__ int lower_bound_i(const int* a, int n, int v) {
    int lo = 0, hi = n;
    while (lo < hi) { int mid = (lo + hi) >> 1; if (a[mid] < v) lo = mid + 1; else hi = mid; }
    return lo;
}

// ---------------- embedding encode (nodes), bf16 out ----------------
__global__ __launch_bounds__(256) void encode_nodes_k(const int* __restrict__ xcat,
                                                      const float* __restrict__ tab,
                                                      ushort_t* __restrict__ X) {
    int n = blockIdx.x, d = threadIdx.x;
    float acc = 0.f;
#pragma unroll
    for (int f = 0; f < NODE_FEATS; ++f) {
        int idx = xcat[n * NODE_FEATS + f];
        acc += tab[((size_t)f * NODE_VOCAB + idx) * D + d];
    }
    X[(size_t)n * D + d] = f2b(acc);
}

// ---------------- CSR build ----------------
__global__ __launch_bounds__(256) void count_k(const int* __restrict__ eidx, int* deg) {
    int e = blockIdx.x * 256 + threadIdx.x;
    if (e < N_EDGES) atomicAdd(&deg[eidx[N_EDGES + e]], 1);
}

#define SCAN_B 1024
__global__ __launch_bounds__(256) void scan1_k(const int* __restrict__ deg,
                                               int* __restrict__ excl, int* __restrict__ bsum) {
    __shared__ int sh[256];
    int b = blockIdx.x, t = threadIdx.x;
    int base = b * SCAN_B + t * 4;
    int d0 = (base + 0) < N_NODES ? deg[base + 0] : 0;
    int d1 = (base + 1) < N_NODES ? deg[base + 1] : 0;
    int d2 = (base + 2) < N_NODES ? deg[base + 2] : 0;
    int d3 = (base + 3) < N_NODES ? deg[base + 3] : 0;
    int s = d0 + d1 + d2 + d3;
    sh[t] = s; __syncthreads();
    for (int off = 1; off < 256; off <<= 1) {
        int x = (t >= off) ? sh[t - off] : 0;
        __syncthreads();
        sh[t] += x;
        __syncthreads();
    }
    int incl = sh[t];
    int ex = incl - s;
    if (base + 0 < N_NODES) excl[base + 0] = ex;
    if (base + 1 < N_NODES) excl[base + 1] = ex + d0;
    if (base + 2 < N_NODES) excl[base + 2] = ex + d0 + d1;
    if (base + 3 < N_NODES) excl[base + 3] = ex + d0 + d1 + d2;
    if (t == 255) bsum[b] = incl;
}

__global__ void scan2_k(int* bsum, int nb) {   // 1 block of 128 threads
    __shared__ int sh[128];
    int t = threadIdx.x;
    int v = (t < nb) ? bsum[t] : 0;
    sh[t] = v; __syncthreads();
    for (int off = 1; off < 128; off <<= 1) {
        int x = (t >= off) ? sh[t - off] : 0;
        __syncthreads();
        sh[t] += x;
        __syncthreads();
    }
    if (t < nb) bsum[t] = sh[t] - v;   // exclusive over blocks
}

__global__ __launch_bounds__(256) void scan3_k(int* __restrict__ offs, int* __restrict__ cursor,
                                               const int* __restrict__ bsum) {
    int i = blockIdx.x * 256 + threadIdx.x;
    if (i < N_NODES) {
        int v = offs[i] + bsum[i >> 10];
        offs[i] = v;
        cursor[i] = v;
    }
}

// elist entry: {src node, packed edge attrs}
__global__ __launch_bounds__(256) void fill_k(const int* __restrict__ eidx,
                                              const int* __restrict__ eattr,
                                              int* cursor, int2* __restrict__ elist) {
    int e = blockIdx.x * 256 + threadIdx.x;
    if (e < N_EDGES) {
        int src = eidx[e];
        int dst = eidx[N_EDGES + e];
        int pa = eattr[e * EDGE_FEATS + 0] | (eattr[e * EDGE_FEATS + 1] << 8)
               | (eattr[e * EDGE_FEATS + 2] << 16);
        int pos = atomicAdd(&cursor[dst], 1);
        elist[pos] = make_int2(src, pa);
    }
}

// -------- gather aggregation: H = bf16(X[n] + sum relu(X[src]+e_emb)) --------
// 4 nodes/block (1 wave each, deg wave-uniform); 2 edges per iteration (dual chains).
__global__ __launch_bounds__(256) void gather_k(const ushort4* __restrict__ X4,
                                                const float4* __restrict__ eemb4,
                                                const int* __restrict__ offs,
                                                const int* __restrict__ deg,
                                                const int2* __restrict__ elist,
                                                ushort4* __restrict__ H4) {
    int n = blockIdx.x * 4 + (threadIdx.x >> 6);
    int lane = threadIdx.x & 63;
    int start = offs[n], dg = deg[n];
    ushort4 xv = X4[(size_t)n * 64 + lane];
    float acc[4] = {b2f(xv.x), b2f(xv.y), b2f(xv.z), b2f(xv.w)};
    for (int i = 0; i < dg; i += 2) {
        bool has1 = (i + 1 < dg);              // wave-uniform
        int2 s0 = elist[start + i];
        int2 s1 = has1 ? elist[start + i + 1] : s0;
        ushort4 v0 = X4[(size_t)s0.x * 64 + lane];
        ushort4 v1 = X4[(size_t)s1.x * 64 + lane];
        float4 a0 = eemb4[(size_t)((s0.y      ) & 255) * 64 + lane];
        float4 a1 = eemb4[((size_t)EDGE_VOCAB + ((s0.y >> 8) & 255)) * 64 + lane];
        float4 a2 = eemb4[((size_t)2 * EDGE_VOCAB + ((s0.y >> 16) & 255)) * 64 + lane];
        acc[0] += fmaxf(b2f(v0.x) + a0.x + a1.x + a2.x, 0.f);
        acc[1] += fmaxf(b2f(v0.y) + a0.y + a1.y + a2.y, 0.f);
        acc[2] += fmaxf(b2f(v0.z) + a0.z + a1.z + a2.z, 0.f);
        acc[3] += fmaxf(b2f(v0.w) + a0.w + a1.w + a2.w, 0.f);
        if (has1) {
            float4 c0 = eemb4[(size_t)((s1.y      ) & 255) * 64 + lane];
            float4 c1 = eemb4[((size_t)EDGE_VOCAB + ((s1.y >> 8) & 255)) * 64 + lane];
            float4 c2 = eemb4[((size_t)2 * EDGE_VOCAB + ((s1.y >> 16) & 255)) * 64 + lane];
            acc[0] += fmaxf(b2f(v1.x) + c0.x + c1.x + c2.x, 0.f);
            acc[1] += fmaxf(b2f(v1.y) + c0.y + c1.y + c2.y, 0.f);
            acc[2] += fmaxf(b2f(v1.z) + c0.z + c1.z + c2.z, 0.f);
            acc[3] += fmaxf(b2f(v1.w) + c0.w + c1.w + c2.w, 0.f);
        }
    }
    ushort4 hv;
    hv.x = f2b(acc[0]); hv.y = f2b(acc[1]); hv.z = f2b(acc[2]); hv.w = f2b(acc[3]);
    H4[(size_t)n * 64 + lane] = hv;
}

// ---------------- weight pre-pack into MFMA fragment layout (bf16) ----------------
__global__ __launch_bounds__(256) void pack1_k(const float* __restrict__ W1, ushort_t* __restrict__ apack) {
    size_t i = (size_t)blockIdx.x * 256 + threadIdx.x;   // 65536 groups
    int l = (int)(i >> 14);
    int rem = (int)(i & 16383);
    int ntg = rem >> 9;
    int rem2 = rem & 511;
    int kk = rem2 >> 6;
    int lane = rem2 & 63;
    int n = ntg * 16 + (lane & 15);
    int k0 = kk * 32 + (lane >> 4) * 8;
    const float* w = W1 + ((size_t)l * D + k0) * D2 + n;
    ushort_t* o = apack + i * 8;
#pragma unroll
    for (int j = 0; j < 8; ++j) o[j] = f2b(w[(size_t)j * D2]);
}

__global__ __launch_bounds__(256) void pack2_k(const float* __restrict__ W2, ushort_t* __restrict__ bpack) {
    size_t i = (size_t)blockIdx.x * 256 + threadIdx.x;   // 65536 groups
    int l = (int)(i >> 14);
    int rem = (int)(i & 16383);
    int ntg = rem >> 10;
    int rem2 = rem & 1023;
    int kk = rem2 >> 6;
    int lane = rem2 & 63;
    int n = ntg * 16 + (lane & 15);
    int k0 = kk * 32 + (lane >> 4) * 8;
    const float* w = W2 + ((size_t)l * D2 + k0) * D + n;
    ushort_t* o = bpack + i * 8;
#pragma unroll
    for (int j = 0; j < 8; ++j) o[j] = f2b(w[(size_t)j * D]);
}

// weight-fragment load helpers (named-register friendly)
#define LDA(h, nt, kk) (*(const bf16x8*)(apack + ((size_t)(((h) * 16 + wid * 2 + (nt)) * 8 + (kk)) * 64 + lane) * 8))
#define LDW(h, nt, kk) (*(const bf16x8*)(bpack + ((size_t)((wid * 2 + (nt)) * 16 + (h) * 8 + (kk)) * 64 + lane) * 8))

// ---------------- fused MFMA MLP: X = relu(relu(H@W1+b1)@W2+b2) ----------------
// 512 threads = 8 waves, BM=64 rows, 64KB LDS -> 2 blocks/CU.
// NAMED prefetch registers (no address-taken locals -> no scratch).
__global__ __launch_bounds__(512, 4) void mlp_k(const ushort_t* __restrict__ H,
                                                const ushort_t* __restrict__ apack,
                                                const float* __restrict__ b1,
                                                const ushort_t* __restrict__ bpack,
                                                const float* __restrict__ b2,
                                                ushort_t* __restrict__ X) {
    __shared__ __align__(16) char hA[BM * 512];    // 32KB: 64 rows x 256 bf16, swizzled
    __shared__ __align__(16) char midh[BM * 512];  // 32KB: one n-half of mid / out stage
    const int t = threadIdx.x;
    const int wid = t >> 6, lane = t & 63;
    const int l15 = lane & 15, g = lane >> 4;
    const size_t r0 = (size_t)blockIdx.x * BM;

    // ---- stage H tile (64 rows, 32KB) with XOR swizzle ----
    {
        const char* src = (const char*)(H + r0 * D);
#pragma unroll
        for (int c = 0; c < 4; ++c) {
            int Lb = (c * 512 + t) * 16;
            int row = Lb >> 9;
            int Sb = Lb ^ ((row & 7) << 4);
            *(uint4*)(hA + Sb) = *(const uint4*)(src + Lb);
        }
    }

    f32x4 acc2[2][4];
#pragma unroll
    for (int a = 0; a < 2; ++a)
#pragma unroll
        for (int b = 0; b < 4; ++b) { f32x4 z = {0.f,0.f,0.f,0.f}; acc2[a][b] = z; }

    // prefetch GEMM1 half-0 first fragments (hides under the staging barrier)
    bf16x8 a0 = LDA(0, 0, 0), a1 = LDA(0, 1, 0);

    __syncthreads();

#pragma unroll
    for (int half = 0; half < 2; ++half) {
        // ---- GEMM1 (transposed): mid[:, half*256 + wid*32 ...] ----
        f32x4 acc1[2][4];
#pragma unroll
        for (int a = 0; a < 2; ++a)
#pragma unroll
            for (int b = 0; b < 4; ++b) { f32x4 z = {0.f,0.f,0.f,0.f}; acc1[a][b] = z; }

#pragma unroll
        for (int kk = 0; kk < 8; ++kk) {
            bf16x8 Bf[4];
#pragma unroll
            for (int mt = 0; mt < 4; ++mt) {
                int m = mt * 16 + l15;
                Bf[mt] = *(const bf16x8*)(hA + ((m * 512 + (kk * 32 + g * 8) * 2) ^ ((m & 7) << 4)));
            }
            bf16x8 n0 = a0, n1 = a1;
            if (kk < 7) { n0 = LDA(half, 0, kk + 1); n1 = LDA(half, 1, kk + 1); }
            __builtin_amdgcn_s_setprio(1);
#pragma unroll
            for (int mt = 0; mt < 4; ++mt)
                acc1[0][mt] = __builtin_amdgcn_mfma_f32_16x16x32_bf16(a0, Bf[mt], acc1[0][mt], 0, 0, 0);
#pragma unroll
            for (int mt = 0; mt < 4; ++mt)
                acc1[1][mt] = __builtin_amdgcn_mfma_f32_16x16x32_bf16(a1, Bf[mt], acc1[1][mt], 0, 0, 0);
            __builtin_amdgcn_s_setprio(0);
            a0 = n0; a1 = n1;
        }

        // prefetch GEMM2 first W2 fragments for this half (hides under pack + barrier)
        bf16x8 w0 = LDW(half, 0, 0), w1 = LDW(half, 1, 0);

        // bias + relu + pack to midh (lane holds 4 consecutive n at fixed m)
#pragma unroll
        for (int nt = 0; nt < 2; ++nt) {
            int n0l = (wid * 2 + nt) * 16 + g * 4;             // local col in half
            f32x4 bv = *(const f32x4*)(b1 + half * 256 + n0l);
#pragma unroll
            for (int mt = 0; mt < 4; ++mt) {
                int m = mt * 16 + l15;
                ushort_t us[4];
#pragma unroll
                for (int r = 0; r < 4; ++r)
                    us[r] = f2b(fmaxf(acc1[nt][mt][r] + bv[r], 0.f));
                uint2 pk;
                pk.x = (uint_t)us[0] | ((uint_t)us[1] << 16);
                pk.y = (uint_t)us[2] | ((uint_t)us[3] << 16);
                *(uint2*)(midh + ((m * 512 + n0l * 2) ^ ((m & 7) << 4))) = pk;
            }
        }
        __syncthreads();   // midh fully written

        // ---- GEMM2 partial (transposed): acc2 += mid_half @ W2[k-half] ----
#pragma unroll
        for (int kk = 0; kk < 8; ++kk) {
            bf16x8 Mf[4];
#pragma unroll
            for (int mt = 0; mt < 4; ++mt) {
                int m = mt * 16 + l15;
                Mf[mt] = *(const bf16x8*)(midh + ((m * 512 + (kk * 32 + g * 8) * 2) ^ ((m & 7) << 4)));
            }
            bf16x8 n0 = w0, n1 = w1;
            if (kk < 7) { n0 = LDW(half, 0, kk + 1); n1 = LDW(half, 1, kk + 1); }
            __builtin_amdgcn_s_setprio(1);
#pragma unroll
            for (int mt = 0; mt < 4; ++mt)
                acc2[0][mt] = __builtin_amdgcn_mfma_f32_16x16x32_bf16(w0, Mf[mt], acc2[0][mt], 0, 0, 0);
#pragma unroll
            for (int mt = 0; mt < 4; ++mt)
                acc2[1][mt] = __builtin_amdgcn_mfma_f32_16x16x32_bf16(w1, Mf[mt], acc2[1][mt], 0, 0, 0);
            __builtin_amdgcn_s_setprio(0);
            w0 = n0; w1 = n1;
        }

        // prefetch next half's GEMM1 first fragments (hides under tail barrier)
        if (half == 0) { a0 = LDA(1, 0, 0); a1 = LDA(1, 1, 0); }
        __syncthreads();   // all reads of midh done before next half overwrites
    }

    // ---- epilogue: stage into midh (swizzled), then coalesced 64B/thread store ----
#pragma unroll
    for (int nt = 0; nt < 2; ++nt) {
        int n0 = (wid * 2 + nt) * 16 + g * 4;
        f32x4 bv = *(const f32x4*)(b2 + n0);
#pragma unroll
        for (int mt = 0; mt < 4; ++mt) {
            int m = mt * 16 + l15;
            ushort_t us[4];
#pragma unroll
            for (int r = 0; r < 4; ++r)
                us[r] = f2b(fmaxf(acc2[nt][mt][r] + bv[r], 0.f));
            uint2 pk;
            pk.x = (uint_t)us[0] | ((uint_t)us[1] << 16);
            pk.y = (uint_t)us[2] | ((uint_t)us[3] << 16);
            *(uint2*)(midh + ((m * 512 + n0 * 2) ^ ((m & 7) << 4))) = pk;
        }
    }
    __syncthreads();
    {
        char* dst = (char*)X + r0 * 512;
#pragma unroll
        for (int j = 0; j < 4; ++j) {
            int Lb = t * 64 + j * 16;
            int row = Lb >> 9;
            int Sb = Lb ^ ((row & 7) << 4);
            *(uint4*)(dst + Lb) = *(const uint4*)(midh + Sb);
        }
    }
}

// -------- fused pooling + final MLP + L2 normalize, GB=8 graphs per block --------
__global__ __launch_bounds__(256) void final_k(const ushort4* __restrict__ X4,
                                               const int* __restrict__ batch,
                                               const float* __restrict__ pW1,
                                               const float* __restrict__ pb1,
                                               const float* __restrict__ pW2,
                                               const float* __restrict__ pb2,
                                               float* __restrict__ out) {
    __shared__ float gin[GB][D];    // 8KB
    __shared__ float mid[GB][D];    // 8KB
    __shared__ float red[GB][256];  // 8KB
    __shared__ int bnd[GB + 1];
    const int g0 = blockIdx.x * GB, t = threadIdx.x;
    const int wid = t >> 6, lane = t & 63;
    if (t <= GB) bnd[t] = lower_bound_i(batch, N_NODES, g0 + t);
    __syncthreads();

    // pooling: wave wid handles graphs wid and wid+4
#pragma unroll
    for (int qq = 0; qq < 2; ++qq) {
        int q = wid + qq * 4;
        f32x4 a = {0.f, 0.f, 0.f, 0.f};
        for (int n = bnd[q]; n < bnd[q + 1]; ++n) {
            ushort4 v = X4[(size_t)n * 64 + lane];
            a.x += b2f(v.x); a.y += b2f(v.y); a.z += b2f(v.z); a.w += b2f(v.w);
        }
        *(f32x4*)&gin[q][lane * 4] = a;
    }
    __syncthreads();

    // mlp1: mid = relu(gin @ pW1 + pb1)
    {
        float m_[GB];
        float bb = pb1[t];
#pragma unroll
        for (int q = 0; q < GB; ++q) m_[q] = bb;
        for (int k = 0; k < D; ++k) {
            float w = pW1[(size_t)k * D + t];
#pragma unroll
            for (int q = 0; q < GB; ++q) m_[q] += gin[q][k] * w;
        }
#pragma unroll
        for (int q = 0; q < GB; ++q) mid[q][t] = fmaxf(m_[q], 0.f);
    }
    __syncthreads();

    // mlp2 + norm
    float a0[GB], a1[GB], a2[GB];
    {
        float b0 = pb2[t], b1_ = pb2[t + 256], b2_ = pb2[t + 512];
#pragma unroll
        for (int q = 0; q < GB; ++q) { a0[q] = b0; a1[q] = b1_; a2[q] = b2_; }
        for (int k = 0; k < D; ++k) {
            float w0 = pW2[(size_t)k * OUTD + t];
            float w1 = pW2[(size_t)k * OUTD + 256 + t];
            float w2 = pW2[(size_t)k * OUTD + 512 + t];
#pragma unroll
            for (int q = 0; q < GB; ++q) {
                float mv = mid[q][k];
                a0[q] += mv * w0; a1[q] += mv * w1; a2[q] += mv * w2;
            }
        }
    }
#pragma unroll
    for (int q = 0; q < GB; ++q)
        red[q][t] = a0[q] * a0[q] + a1[q] * a1[q] + a2[q] * a2[q];
    __syncthreads();
    for (int s = 128; s > 0; s >>= 1) {
        if (t < s) {
#pragma unroll
            for (int q = 0; q < GB; ++q) red[q][t] += red[q][t + s];
        }
        __syncthreads();
    }
#pragma unroll
    for (int q = 0; q < GB; ++q) {
        float inv = 1.f / fmaxf(sqrtf(red[q][0]), 1e-12f);
        out[(size_t)(g0 + q) * OUTD + t]       = a0[q] * inv;
        out[(size_t)(g0 + q) * OUTD + 256 + t] = a1[q] * inv;
        out[(size_t)(g0 + q) * OUTD + 512 + t] = a2[q] * inv;
    }
}

extern "C" void kernel_launch(void* const* d_in, const int* in_sizes, int n_in,
                              void* d_out, int out_size, void* d_ws, size_t ws_size,
                              hipStream_t stream) {
    const int*   x_cat      = (const int*)d_in[0];
    const int*   edge_attr  = (const int*)d_in[1];
    const int*   edge_index = (const int*)d_in[2];
    const int*   batch      = (const int*)d_in[3];
    const float* node_emb   = (const float*)d_in[4];
    const float* edge_emb   = (const float*)d_in[5];
    const float* W1  = (const float*)d_in[6];
    const float* b1  = (const float*)d_in[7];
    const float* W2  = (const float*)d_in[8];
    const float* b2  = (const float*)d_in[9];
    const float* pW1 = (const float*)d_in[10];
    const float* pb1 = (const float*)d_in[11];
    const float* pW2 = (const float*)d_in[12];
    const float* pb2 = (const float*)d_in[13];
    float* out = (float*)d_out;

    // ---- workspace carve (~112 MB) ----
    char* p = (char*)d_ws;
    auto carve = [&](size_t bytes) { char* q = p; p += (bytes + 255) & ~(size_t)255; return q; };
    ushort_t* X      = (ushort_t*)carve((size_t)N_NODES_PAD * D * 2);   // 51.2 MB
    ushort_t* H      = (ushort_t*)carve((size_t)N_NODES_PAD * D * 2);   // 51.2 MB
    int*      deg    = (int*)carve((size_t)N_NODES * 4);
    int*      offs   = (int*)carve((size_t)(N_NODES + 8) * 4);
    int*      cursor = (int*)carve((size_t)(N_NODES + 8) * 4);
    int*      bsum   = (int*)carve(1024);
    int2*     elist  = (int2*)carve((size_t)N_EDGES * 8);
    ushort_t* apack1 = (ushort_t*)carve((size_t)LAYERS * 32 * 8 * 64 * 8 * 2);   // 2 MB
    ushort_t* bpack2 = (ushort_t*)carve((size_t)LAYERS * 16 * 16 * 64 * 8 * 2);  // 2 MB

    const int NB = (N_NODES + SCAN_B - 1) / SCAN_B;   // 98

    // ---- one-time per call: weight pre-pack + CSR build ----
    pack1_k<<<256, 256, 0, stream>>>(W1, apack1);
    pack2_k<<<256, 256, 0, stream>>>(W2, bpack2);
    hipMemsetAsync(deg, 0, (size_t)N_NODES * 4, stream);
    count_k<<<(N_EDGES + 255) / 256, 256, 0, stream>>>(edge_index, deg);
    scan1_k<<<NB, 256, 0, stream>>>(deg, offs, bsum);
    scan2_k<<<1, 128, 0, stream>>>(bsum, NB);
    scan3_k<<<(N_NODES + 255) / 256, 256, 0, stream>>>(offs, cursor, bsum);
    fill_k<<<(N_EDGES + 255) / 256, 256, 0, stream>>>(edge_index, edge_attr, cursor, elist);

    encode_nodes_k<<<N_NODES, 256, 0, stream>>>(x_cat, node_emb, X);

    for (int l = 0; l < LAYERS; ++l) {
        gather_k<<<N_NODES / 4, 256, 0, stream>>>((const ushort4*)X, (const float4*)edge_emb,
                                                  offs, deg, elist, (ushort4*)H);
        mlp_k<<<N_NODES_PAD / BM, 512, 0, stream>>>(
            H,
            apack1 + (size_t)l * 32 * 8 * 64 * 8,
            b1 + (size_t)l * D2,
            bpack2 + (size_t)l * 16 * 16 * 64 * 8,
            b2 + (size_t)l * D,
            X);
    }

    final_k<<<N_GRAPHS / GB, 256, 0, stream>>>((const ushort4*)X, batch, pW1, pb1, pW2, pb2, out);
}